// Round 14
// baseline (215.893 us; speedup 1.0000x reference)
//
#include <hip/hip_runtime.h>
#include <hip/hip_fp16.h>

// GAT forward on MI355X (gfx950) — fixed-capacity CSR (direct scatter), fp16 feat,
// MFMA feat+residual GEMM fused, phase-sequential blocks. 3 stream ops.
//
// Pipeline:
//  memset : counts[N] = 0
//  k1     : ALL blocks: phase A (grid-stride tiles): feat GEMM (8 MFMA) + residual GEMM
//           (2 MFMA, same A-frags) + el4/er4 + fp16 featH + out init;
//           then phase B (grid-stride edges): slot=atomicAdd(counts[dst]);
//           srcS[dst*128+slot]=src
//  k2     : wave per 4 dst nodes lockstep; fdot2 fp16 gathers; out += (residual pre-init)

typedef _Float16 f16x8 __attribute__((ext_vector_type(8)));
typedef _Float16 h2 __attribute__((ext_vector_type(2)));
typedef float f32x4 __attribute__((ext_vector_type(4)));

#define NBLK1 1024
#define CAP   128   // per-node srcS capacity; P(deg>128) ~ 1e-80

__device__ __forceinline__ float rflf(float v) {
    return __int_as_float(__builtin_amdgcn_readfirstlane(__float_as_int(v)));
}

__global__ __launch_bounds__(256) void k1(
    const int* __restrict__ src, const int* __restrict__ dst,
    int* __restrict__ counts, int* __restrict__ srcS, int E,
    const float* __restrict__ emb, const float* __restrict__ Wfc,
    const float* __restrict__ attnl, const float* __restrict__ attnr,
    __half* __restrict__ featH, float* __restrict__ el4, float* __restrict__ er4,
    const float* __restrict__ Wres, const float* __restrict__ bias,
    float* __restrict__ out, int N) {
    __shared__ _Float16 ftH[16][264];   // 8.25 KiB padded bounce tile
    int tid = threadIdx.x;
    int bx = blockIdx.x;
    int lane = tid & 63, w = tid >> 6;      // wave w owns head w (feat) / cols w*16.. (res)
    int lrow = lane & 15;
    int lgrp = lane >> 4;

    // ---- prologue: B-fragments (fp16) for Wfc (feat) and head-mean Wres (residual) ----
    f16x8 bf[8];
#pragma unroll
    for (int ct = 0; ct < 4; ++ct)
#pragma unroll
        for (int kh = 0; kh < 2; ++kh) {
#pragma unroll
            for (int i = 0; i < 8; ++i) {
                int k = kh * 32 + lgrp * 8 + i;
                int c = (w << 6) + (ct << 4) + lrow;
                bf[ct * 2 + kh][i] = (_Float16)Wfc[k * 256 + c];
            }
        }
    f16x8 rf[2];
    {
        int c = (w << 4) + lrow;   // residual out col 0..63
#pragma unroll
        for (int kh = 0; kh < 2; ++kh)
#pragma unroll
            for (int i = 0; i < 8; ++i) {
                int k = kh * 32 + lgrp * 8 + i;
                const float* p = Wres + k * 256 + c;
                rf[kh][i] = (_Float16)(0.25f * (p[0] + p[64] + p[128] + p[192]));
            }
    }
    float bm;
    {
        int c = (w << 4) + lrow;
        bm = 0.25f * (bias[c] + bias[64 + c] + bias[128 + c] + bias[192 + c]);
    }
    float alr[4], arr[4];
#pragma unroll
    for (int ct = 0; ct < 4; ++ct) {
        int c = (w << 6) + (ct << 4) + lrow;
        alr[ct] = attnl[c];
        arr[ct] = attnr[c];
    }

    // ---- phase A: feat + residual GEMM over grid-strided 16-node tiles ----
    int ntiles = N >> 4;   // N % 16 == 0
    for (int tile = bx; tile < ntiles; tile += NBLK1) {
        int n0 = tile << 4;
        const float* arow = emb + (size_t)(n0 + lrow) * 64 + lgrp * 8;
        float4 a0 = *(const float4*)arow;
        float4 a1 = *(const float4*)(arow + 4);
        float4 a2 = *(const float4*)(arow + 32);
        float4 a3 = *(const float4*)(arow + 36);
        f16x8 af0, af1;
        af0[0] = (_Float16)a0.x; af0[1] = (_Float16)a0.y;
        af0[2] = (_Float16)a0.z; af0[3] = (_Float16)a0.w;
        af0[4] = (_Float16)a1.x; af0[5] = (_Float16)a1.y;
        af0[6] = (_Float16)a1.z; af0[7] = (_Float16)a1.w;
        af1[0] = (_Float16)a2.x; af1[1] = (_Float16)a2.y;
        af1[2] = (_Float16)a2.z; af1[3] = (_Float16)a2.w;
        af1[4] = (_Float16)a3.x; af1[5] = (_Float16)a3.y;
        af1[6] = (_Float16)a3.z; af1[7] = (_Float16)a3.w;

        // residual: [16x64] = A[16x64] @ Wm[64x64], wave w covers cols w*16..+15
        f32x4 accR = (f32x4){0.f, 0.f, 0.f, 0.f};
        accR = __builtin_amdgcn_mfma_f32_16x16x32_f16(af0, rf[0], accR, 0, 0, 0);
        accR = __builtin_amdgcn_mfma_f32_16x16x32_f16(af1, rf[1], accR, 0, 0, 0);
#pragma unroll
        for (int i = 0; i < 4; ++i) {
            int n = n0 + (lgrp << 2) + i;
            out[(size_t)n * 64 + (w << 4) + lrow] = accR[i] + bm;
        }

        // feat: wave w covers cols w*64..+63 (head w)
        f32x4 acc[4];
#pragma unroll
        for (int ct = 0; ct < 4; ++ct) acc[ct] = (f32x4){0.f, 0.f, 0.f, 0.f};
#pragma unroll
        for (int ct = 0; ct < 4; ++ct) {
            acc[ct] = __builtin_amdgcn_mfma_f32_16x16x32_f16(af0, bf[ct * 2 + 0], acc[ct], 0, 0, 0);
            acc[ct] = __builtin_amdgcn_mfma_f32_16x16x32_f16(af1, bf[ct * 2 + 1], acc[ct], 0, 0, 0);
        }

        float pl[4], pr[4];
#pragma unroll
        for (int i = 0; i < 4; ++i) {
            pl[i] = acc[0][i] * alr[0] + acc[1][i] * alr[1] +
                    acc[2][i] * alr[2] + acc[3][i] * alr[3];
            pr[i] = acc[0][i] * arr[0] + acc[1][i] * arr[1] +
                    acc[2][i] * arr[2] + acc[3][i] * arr[3];
        }
#pragma unroll
        for (int off = 1; off < 16; off <<= 1)
#pragma unroll
            for (int i = 0; i < 4; ++i) {
                pl[i] += __shfl_xor(pl[i], off);
                pr[i] += __shfl_xor(pr[i], off);
            }
        if (lrow == 0) {
#pragma unroll
            for (int i = 0; i < 4; ++i) {
                int n = n0 + (lgrp << 2) + i;
                el4[n * 4 + w] = pl[i];
                er4[n * 4 + w] = pr[i];
            }
        }

#pragma unroll
        for (int ct = 0; ct < 4; ++ct)
#pragma unroll
            for (int i = 0; i < 4; ++i)
                ftH[(lgrp << 2) + i][(((ct << 4) + lrow) << 2) + w] = (_Float16)acc[ct][i];
        __syncthreads();
        {
            uint4* gdst = (uint4*)(featH + (size_t)n0 * 256);
#pragma unroll
            for (int it = 0; it < 2; ++it) {
                int chunk = it * 256 + tid;
                int row = chunk >> 5, c16 = chunk & 31;
                gdst[chunk] = *(const uint4*)&ftH[row][c16 * 8];
            }
        }
        __syncthreads();
    }

    // ---- phase B: histogram + direct scatter (grid-stride, all blocks) ----
    for (int e = bx * 256 + tid; e < E; e += NBLK1 * 256) {
        int t = dst[e];
        int s = src[e];
        int slot = atomicAdd(&counts[t], 1);
        if (slot < CAP) srcS[((size_t)t << 7) + slot] = s;
    }
}

// wave per 4 dst nodes, lockstep; srcS at fixed stride CAP; out += (residual pre-init).
__global__ __launch_bounds__(256) void k_agg(const int* __restrict__ counts,
                                             const int* __restrict__ srcS,
                                             const float* __restrict__ el4,
                                             const float* __restrict__ er4,
                                             const __half* __restrict__ featH,
                                             float* __restrict__ out, int N) {
    int tid = threadIdx.x;
    int lane = tid & 63;
    int nbase = blockIdx.x * 16 + ((tid >> 6) << 2);

    float base_o[4];
#pragma unroll
    for (int r = 0; r < 4; ++r)
        base_o[r] = out[(size_t)(nbase + r) * 64 + lane];

    int4 ct4 = *(const int4*)(counts + nbase);
    int cnt_[4] = {min(ct4.x, CAP), min(ct4.y, CAP), min(ct4.z, CAP), min(ct4.w, CAP)};
    int mmax = 1;
#pragma unroll
    for (int r = 0; r < 4; ++r) mmax = cnt_[r] > mmax ? cnt_[r] : mmax;

    if (mmax <= 64) {
        float4 e4_[4];
        int sj_[4];
#pragma unroll
        for (int r = 0; r < 4; ++r) {
            e4_[r] = (float4){0.f, 0.f, 0.f, 0.f};
            sj_[r] = 0;
            if (lane < cnt_[r]) sj_[r] = srcS[((size_t)(nbase + r) << 7) + lane];
        }
#pragma unroll
        for (int r = 0; r < 4; ++r) {
            if (lane < cnt_[r]) {
                float4 ern = *(const float4*)(er4 + 4 * (size_t)(nbase + r));
                float4 l = *(const float4*)(el4 + 4 * (size_t)sj_[r]);
                float x0 = l.x + ern.x, x1 = l.y + ern.y;
                float x2 = l.z + ern.z, x3 = l.w + ern.w;
                x0 = x0 > 0.f ? x0 : 0.2f * x0;
                x1 = x1 > 0.f ? x1 : 0.2f * x1;
                x2 = x2 > 0.f ? x2 : 0.2f * x2;
                x3 = x3 > 0.f ? x3 : 0.2f * x3;
                e4_[r].x = __expf(x0); e4_[r].y = __expf(x1);
                e4_[r].z = __expf(x2); e4_[r].w = __expf(x3);
            }
        }
        float4 den_[4];
#pragma unroll
        for (int r = 0; r < 4; ++r) den_[r] = e4_[r];
        for (int off = 1; off < mmax; off <<= 1) {
#pragma unroll
            for (int r = 0; r < 4; ++r) {
                den_[r].x += __shfl_xor(den_[r].x, off);
                den_[r].y += __shfl_xor(den_[r].y, off);
                den_[r].z += __shfl_xor(den_[r].z, off);
                den_[r].w += __shfl_xor(den_[r].w, off);
            }
        }
        int pk01_[4], pk23_[4];
#pragma unroll
        for (int r = 0; r < 4; ++r) {
            float ivx = 0.25f * __builtin_amdgcn_rcpf(rflf(den_[r].x));
            float ivy = 0.25f * __builtin_amdgcn_rcpf(rflf(den_[r].y));
            float ivz = 0.25f * __builtin_amdgcn_rcpf(rflf(den_[r].z));
            float ivw = 0.25f * __builtin_amdgcn_rcpf(rflf(den_[r].w));
            auto c01 = __builtin_amdgcn_cvt_pkrtz(e4_[r].x * ivx, e4_[r].y * ivy);
            auto c23 = __builtin_amdgcn_cvt_pkrtz(e4_[r].z * ivz, e4_[r].w * ivw);
            pk01_[r] = __builtin_bit_cast(int, c01);
            pk23_[r] = __builtin_bit_cast(int, c23);
        }
        float accA_[4], accB_[4], accC_[4], accD_[4];
#pragma unroll
        for (int r = 0; r < 4; ++r) { accA_[r] = accB_[r] = accC_[r] = accD_[r] = 0.f; }
        for (int j0 = 0; j0 < mmax; j0 += 4) {
            uint2 u[4][4];
#pragma unroll
            for (int r = 0; r < 4; ++r) {
                if (j0 < cnt_[r]) {
#pragma unroll
                    for (int q = 0; q < 4; ++q) {
                        int s = __builtin_amdgcn_readlane(sj_[r], j0 + q);
                        u[r][q] = *(const uint2*)(featH + ((size_t)s << 8) + (lane << 2));
                    }
                }
            }
#pragma unroll
            for (int r = 0; r < 4; ++r) {
                if (j0 < cnt_[r]) {
#pragma unroll
                    for (int q = 0; q < 4; ++q) {
                        int a01 = __builtin_amdgcn_readlane(pk01_[r], j0 + q);
                        int a23 = __builtin_amdgcn_readlane(pk23_[r], j0 + q);
                        h2 f01 = __builtin_bit_cast(h2, u[r][q].x);
                        h2 f23 = __builtin_bit_cast(h2, u[r][q].y);
                        h2 w01 = __builtin_bit_cast(h2, a01);
                        h2 w23 = __builtin_bit_cast(h2, a23);
                        if (q & 1) {
                            accC_[r] = __builtin_amdgcn_fdot2(f01, w01, accC_[r], false);
                            accD_[r] = __builtin_amdgcn_fdot2(f23, w23, accD_[r], false);
                        } else {
                            accA_[r] = __builtin_amdgcn_fdot2(f01, w01, accA_[r], false);
                            accB_[r] = __builtin_amdgcn_fdot2(f23, w23, accB_[r], false);
                        }
                    }
                }
            }
        }
#pragma unroll
        for (int r = 0; r < 4; ++r)
            out[(size_t)(nbase + r) * 64 + lane] =
                base_o[r] + ((accA_[r] + accC_[r]) + (accB_[r] + accD_[r]));
        return;
    }

    // slow path (any node with cnt in (64,128])
    for (int r = 0; r < 4; ++r) {
        int n = nbase + r;
        int cnt = cnt_[r];
        size_t start = (size_t)n << 7;
        if (cnt == 0) { out[(size_t)n * 64 + lane] = base_o[r]; continue; }
        float4 ern = *(const float4*)(er4 + 4 * (size_t)n);
        float4 den = {0.f, 0.f, 0.f, 0.f};
        for (int i0 = 0; i0 < cnt; i0 += 64) {
            int m = min(64, cnt - i0);
            float4 e4 = {0.f, 0.f, 0.f, 0.f};
            if (lane < m) {
                int sj = srcS[start + i0 + lane];
                float4 l = *(const float4*)(el4 + 4 * (size_t)sj);
                float x0 = l.x + ern.x, x1 = l.y + ern.y;
                float x2 = l.z + ern.z, x3 = l.w + ern.w;
                x0 = x0 > 0.f ? x0 : 0.2f * x0;
                x1 = x1 > 0.f ? x1 : 0.2f * x1;
                x2 = x2 > 0.f ? x2 : 0.2f * x2;
                x3 = x3 > 0.f ? x3 : 0.2f * x3;
                e4.x = __expf(x0); e4.y = __expf(x1);
                e4.z = __expf(x2); e4.w = __expf(x3);
            }
            den.x += e4.x; den.y += e4.y; den.z += e4.z; den.w += e4.w;
        }
#pragma unroll
        for (int off = 32; off; off >>= 1) {
            den.x += __shfl_xor(den.x, off);
            den.y += __shfl_xor(den.y, off);
            den.z += __shfl_xor(den.z, off);
            den.w += __shfl_xor(den.w, off);
        }
        float ivx = 0.25f * __builtin_amdgcn_rcpf(den.x);
        float ivy = 0.25f * __builtin_amdgcn_rcpf(den.y);
        float ivz = 0.25f * __builtin_amdgcn_rcpf(den.z);
        float ivw = 0.25f * __builtin_amdgcn_rcpf(den.w);
        float accA = 0.f, accB = 0.f;
        for (int i0 = 0; i0 < cnt; i0 += 64) {
            int m = min(64, cnt - i0);
            float4 e4 = {0.f, 0.f, 0.f, 0.f};
            int sj = 0;
            if (lane < m) {
                sj = srcS[start + i0 + lane];
                float4 l = *(const float4*)(el4 + 4 * (size_t)sj);
                float x0 = l.x + ern.x, x1 = l.y + ern.y;
                float x2 = l.z + ern.z, x3 = l.w + ern.w;
                x0 = x0 > 0.f ? x0 : 0.2f * x0;
                x1 = x1 > 0.f ? x1 : 0.2f * x1;
                x2 = x2 > 0.f ? x2 : 0.2f * x2;
                x3 = x3 > 0.f ? x3 : 0.2f * x3;
                e4.x = __expf(x0); e4.y = __expf(x1);
                e4.z = __expf(x2); e4.w = __expf(x3);
            }
            auto c01 = __builtin_amdgcn_cvt_pkrtz(e4.x * ivx, e4.y * ivy);
            auto c23 = __builtin_amdgcn_cvt_pkrtz(e4.z * ivz, e4.w * ivw);
            int pk01 = __builtin_bit_cast(int, c01);
            int pk23 = __builtin_bit_cast(int, c23);
            for (int j = 0; j < m; ++j) {
                int s = __builtin_amdgcn_readlane(sj, j);
                uint2 u = *(const uint2*)(featH + ((size_t)s << 8) + (lane << 2));
                int a01 = __builtin_amdgcn_readlane(pk01, j);
                int a23 = __builtin_amdgcn_readlane(pk23, j);
                accA = __builtin_amdgcn_fdot2(__builtin_bit_cast(h2, u.x),
                                              __builtin_bit_cast(h2, a01), accA, false);
                accB = __builtin_amdgcn_fdot2(__builtin_bit_cast(h2, u.y),
                                              __builtin_bit_cast(h2, a23), accB, false);
            }
        }
        out[(size_t)n * 64 + lane] = base_o[r] + accA + accB;
    }
}

extern "C" void kernel_launch(void* const* d_in, const int* in_sizes, int n_in,
                              void* d_out, int out_size, void* d_ws, size_t ws_size,
                              hipStream_t stream) {
    const float* emb   = (const float*)d_in[0];
    const float* Wfc   = (const float*)d_in[1];
    const float* attnl = (const float*)d_in[2];
    const float* attnr = (const float*)d_in[3];
    const float* Wres  = (const float*)d_in[4];
    const float* bias  = (const float*)d_in[5];
    const int*   src   = (const int*)d_in[6];
    const int*   dst   = (const int*)d_in[7];
    int N = in_sizes[0] / 64;
    int E = in_sizes[6];
    float* out = (float*)d_out;

    // workspace
    __half* featH  = (__half*)d_ws;                        // N*256 fp16
    float*  el4    = (float*)(featH + (size_t)N * 256);    // N*4
    float*  er4    = el4 + (size_t)N * 4;                  // N*4
    int*    counts = (int*)(er4 + (size_t)N * 4);          // N
    int*    srcS   = counts + N;                           // N*CAP

    (void)hipMemsetAsync(counts, 0, (size_t)N * sizeof(int), stream);

    hipLaunchKernelGGL(k1, dim3(NBLK1), dim3(256), 0, stream,
                       src, dst, counts, srcS, E,
                       emb, Wfc, attnl, attnr, featH, el4, er4, Wres, bias, out, N);
    hipLaunchKernelGGL(k_agg, dim3(N / 16), dim3(256), 0, stream,
                       counts, srcS, el4, er4, featH, out, N);
}

// Round 15
// 191.671 us; speedup vs baseline: 1.1264x; 1.1264x over previous
//
#include <hip/hip_runtime.h>
#include <hip/hip_fp16.h>

// GAT forward on MI355X (gfx950) — fixed-capacity CSR (direct scatter), fp16 feat,
// MFMA feat+residual GEMM fused, CONCURRENT role-split (hist atomic wall hides GEMM).
// 3 stream ops.
//
// Pipeline:
//  memset : counts[N] = 0
//  k1     : blocks [0,NG)  : feat GEMM (8 MFMA) + residual GEMM (2 MFMA, same A-frags)
//                            + el4/er4 + fp16 featH + out init   (grid-stride tiles)
//           blocks [NG,..) : slot=atomicAdd(counts[dst]); srcS[dst*128+slot]=src
//                            (runs CONCURRENTLY — atomic-throughput-capped, hides GEMM)
//  k2     : wave per 4 dst nodes lockstep; fdot2 fp16 gathers; out += (residual pre-init)

typedef _Float16 f16x8 __attribute__((ext_vector_type(8)));
typedef _Float16 h2 __attribute__((ext_vector_type(2)));
typedef float f32x4 __attribute__((ext_vector_type(4)));

#define NG    384
#define NH    640
#define CAP   128   // per-node srcS capacity; P(deg>128) ~ 1e-80

__device__ __forceinline__ float rflf(float v) {
    return __int_as_float(__builtin_amdgcn_readfirstlane(__float_as_int(v)));
}

__global__ __launch_bounds__(256) void k1(
    const int* __restrict__ src, const int* __restrict__ dst,
    int* __restrict__ counts, int* __restrict__ srcS, int E,
    const float* __restrict__ emb, const float* __restrict__ Wfc,
    const float* __restrict__ attnl, const float* __restrict__ attnr,
    __half* __restrict__ featH, float* __restrict__ el4, float* __restrict__ er4,
    const float* __restrict__ Wres, const float* __restrict__ bias,
    float* __restrict__ out, int N) {
    __shared__ _Float16 ftH[16][264];   // 8.25 KiB padded bounce tile
    int tid = threadIdx.x;
    int bx = blockIdx.x;

    if (bx >= NG) {   // ---- hist + direct scatter (concurrent with GEMM role) ----
        for (int e = (bx - NG) * 256 + tid; e < E; e += NH * 256) {
            int t = dst[e];
            int s = src[e];
            int slot = atomicAdd(&counts[t], 1);
            if (slot < CAP) srcS[((size_t)t << 7) + slot] = s;
        }
        return;
    }

    // ---- GEMM role: feat + residual via MFMA ----
    int lane = tid & 63, w = tid >> 6;      // wave w: head w (feat), cols w*16.. (res)
    int lrow = lane & 15;
    int lgrp = lane >> 4;

    f16x8 bf[8];
#pragma unroll
    for (int ct = 0; ct < 4; ++ct)
#pragma unroll
        for (int kh = 0; kh < 2; ++kh) {
#pragma unroll
            for (int i = 0; i < 8; ++i) {
                int k = kh * 32 + lgrp * 8 + i;
                int c = (w << 6) + (ct << 4) + lrow;
                bf[ct * 2 + kh][i] = (_Float16)Wfc[k * 256 + c];
            }
        }
    f16x8 rf[2];
    {
        int c = (w << 4) + lrow;   // residual out col 0..63
#pragma unroll
        for (int kh = 0; kh < 2; ++kh)
#pragma unroll
            for (int i = 0; i < 8; ++i) {
                int k = kh * 32 + lgrp * 8 + i;
                const float* p = Wres + k * 256 + c;
                rf[kh][i] = (_Float16)(0.25f * (p[0] + p[64] + p[128] + p[192]));
            }
    }
    float bm;
    {
        int c = (w << 4) + lrow;
        bm = 0.25f * (bias[c] + bias[64 + c] + bias[128 + c] + bias[192 + c]);
    }
    float alr[4], arr[4];
#pragma unroll
    for (int ct = 0; ct < 4; ++ct) {
        int c = (w << 6) + (ct << 4) + lrow;
        alr[ct] = attnl[c];
        arr[ct] = attnr[c];
    }

    int ntiles = N >> 4;   // N % 16 == 0
    for (int tile = bx; tile < ntiles; tile += NG) {
        int n0 = tile << 4;
        const float* arow = emb + (size_t)(n0 + lrow) * 64 + lgrp * 8;
        float4 a0 = *(const float4*)arow;
        float4 a1 = *(const float4*)(arow + 4);
        float4 a2 = *(const float4*)(arow + 32);
        float4 a3 = *(const float4*)(arow + 36);
        f16x8 af0, af1;
        af0[0] = (_Float16)a0.x; af0[1] = (_Float16)a0.y;
        af0[2] = (_Float16)a0.z; af0[3] = (_Float16)a0.w;
        af0[4] = (_Float16)a1.x; af0[5] = (_Float16)a1.y;
        af0[6] = (_Float16)a1.z; af0[7] = (_Float16)a1.w;
        af1[0] = (_Float16)a2.x; af1[1] = (_Float16)a2.y;
        af1[2] = (_Float16)a2.z; af1[3] = (_Float16)a2.w;
        af1[4] = (_Float16)a3.x; af1[5] = (_Float16)a3.y;
        af1[6] = (_Float16)a3.z; af1[7] = (_Float16)a3.w;

        // residual: out init = A @ Wm + bm  (wave w covers cols w*16..+15)
        f32x4 accR = (f32x4){0.f, 0.f, 0.f, 0.f};
        accR = __builtin_amdgcn_mfma_f32_16x16x32_f16(af0, rf[0], accR, 0, 0, 0);
        accR = __builtin_amdgcn_mfma_f32_16x16x32_f16(af1, rf[1], accR, 0, 0, 0);
#pragma unroll
        for (int i = 0; i < 4; ++i) {
            int n = n0 + (lgrp << 2) + i;
            out[(size_t)n * 64 + (w << 4) + lrow] = accR[i] + bm;
        }

        // feat: wave w covers cols w*64..+63 (head w)
        f32x4 acc[4];
#pragma unroll
        for (int ct = 0; ct < 4; ++ct) acc[ct] = (f32x4){0.f, 0.f, 0.f, 0.f};
#pragma unroll
        for (int ct = 0; ct < 4; ++ct) {
            acc[ct] = __builtin_amdgcn_mfma_f32_16x16x32_f16(af0, bf[ct * 2 + 0], acc[ct], 0, 0, 0);
            acc[ct] = __builtin_amdgcn_mfma_f32_16x16x32_f16(af1, bf[ct * 2 + 1], acc[ct], 0, 0, 0);
        }

        float pl[4], pr[4];
#pragma unroll
        for (int i = 0; i < 4; ++i) {
            pl[i] = acc[0][i] * alr[0] + acc[1][i] * alr[1] +
                    acc[2][i] * alr[2] + acc[3][i] * alr[3];
            pr[i] = acc[0][i] * arr[0] + acc[1][i] * arr[1] +
                    acc[2][i] * arr[2] + acc[3][i] * arr[3];
        }
#pragma unroll
        for (int off = 1; off < 16; off <<= 1)
#pragma unroll
            for (int i = 0; i < 4; ++i) {
                pl[i] += __shfl_xor(pl[i], off);
                pr[i] += __shfl_xor(pr[i], off);
            }
        if (lrow == 0) {
#pragma unroll
            for (int i = 0; i < 4; ++i) {
                int n = n0 + (lgrp << 2) + i;
                el4[n * 4 + w] = pl[i];
                er4[n * 4 + w] = pr[i];
            }
        }

#pragma unroll
        for (int ct = 0; ct < 4; ++ct)
#pragma unroll
            for (int i = 0; i < 4; ++i)
                ftH[(lgrp << 2) + i][(((ct << 4) + lrow) << 2) + w] = (_Float16)acc[ct][i];
        __syncthreads();
        {
            uint4* gdst = (uint4*)(featH + (size_t)n0 * 256);
#pragma unroll
            for (int it = 0; it < 2; ++it) {
                int chunk = it * 256 + tid;
                int row = chunk >> 5, c16 = chunk & 31;
                gdst[chunk] = *(const uint4*)&ftH[row][c16 * 8];
            }
        }
        __syncthreads();
    }
}

// wave per 4 dst nodes, lockstep; srcS at fixed stride CAP; out += (residual pre-init).
__global__ __launch_bounds__(256) void k_agg(const int* __restrict__ counts,
                                             const int* __restrict__ srcS,
                                             const float* __restrict__ el4,
                                             const float* __restrict__ er4,
                                             const __half* __restrict__ featH,
                                             float* __restrict__ out, int N) {
    int tid = threadIdx.x;
    int lane = tid & 63;
    int nbase = blockIdx.x * 16 + ((tid >> 6) << 2);

    float base_o[4];
#pragma unroll
    for (int r = 0; r < 4; ++r)
        base_o[r] = out[(size_t)(nbase + r) * 64 + lane];

    int4 ct4 = *(const int4*)(counts + nbase);
    int cnt_[4] = {min(ct4.x, CAP), min(ct4.y, CAP), min(ct4.z, CAP), min(ct4.w, CAP)};
    int mmax = 1;
#pragma unroll
    for (int r = 0; r < 4; ++r) mmax = cnt_[r] > mmax ? cnt_[r] : mmax;

    if (mmax <= 64) {
        float4 e4_[4];
        int sj_[4];
#pragma unroll
        for (int r = 0; r < 4; ++r) {
            e4_[r] = (float4){0.f, 0.f, 0.f, 0.f};
            sj_[r] = 0;
            if (lane < cnt_[r]) sj_[r] = srcS[((size_t)(nbase + r) << 7) + lane];
        }
#pragma unroll
        for (int r = 0; r < 4; ++r) {
            if (lane < cnt_[r]) {
                float4 ern = *(const float4*)(er4 + 4 * (size_t)(nbase + r));
                float4 l = *(const float4*)(el4 + 4 * (size_t)sj_[r]);
                float x0 = l.x + ern.x, x1 = l.y + ern.y;
                float x2 = l.z + ern.z, x3 = l.w + ern.w;
                x0 = x0 > 0.f ? x0 : 0.2f * x0;
                x1 = x1 > 0.f ? x1 : 0.2f * x1;
                x2 = x2 > 0.f ? x2 : 0.2f * x2;
                x3 = x3 > 0.f ? x3 : 0.2f * x3;
                e4_[r].x = __expf(x0); e4_[r].y = __expf(x1);
                e4_[r].z = __expf(x2); e4_[r].w = __expf(x3);
            }
        }
        float4 den_[4];
#pragma unroll
        for (int r = 0; r < 4; ++r) den_[r] = e4_[r];
        for (int off = 1; off < mmax; off <<= 1) {
#pragma unroll
            for (int r = 0; r < 4; ++r) {
                den_[r].x += __shfl_xor(den_[r].x, off);
                den_[r].y += __shfl_xor(den_[r].y, off);
                den_[r].z += __shfl_xor(den_[r].z, off);
                den_[r].w += __shfl_xor(den_[r].w, off);
            }
        }
        int pk01_[4], pk23_[4];
#pragma unroll
        for (int r = 0; r < 4; ++r) {
            float ivx = 0.25f * __builtin_amdgcn_rcpf(rflf(den_[r].x));
            float ivy = 0.25f * __builtin_amdgcn_rcpf(rflf(den_[r].y));
            float ivz = 0.25f * __builtin_amdgcn_rcpf(rflf(den_[r].z));
            float ivw = 0.25f * __builtin_amdgcn_rcpf(rflf(den_[r].w));
            auto c01 = __builtin_amdgcn_cvt_pkrtz(e4_[r].x * ivx, e4_[r].y * ivy);
            auto c23 = __builtin_amdgcn_cvt_pkrtz(e4_[r].z * ivz, e4_[r].w * ivw);
            pk01_[r] = __builtin_bit_cast(int, c01);
            pk23_[r] = __builtin_bit_cast(int, c23);
        }
        float accA_[4], accB_[4], accC_[4], accD_[4];
#pragma unroll
        for (int r = 0; r < 4; ++r) { accA_[r] = accB_[r] = accC_[r] = accD_[r] = 0.f; }
        for (int j0 = 0; j0 < mmax; j0 += 4) {
            uint2 u[4][4];
#pragma unroll
            for (int r = 0; r < 4; ++r) {
                if (j0 < cnt_[r]) {
#pragma unroll
                    for (int q = 0; q < 4; ++q) {
                        int s = __builtin_amdgcn_readlane(sj_[r], j0 + q);
                        u[r][q] = *(const uint2*)(featH + ((size_t)s << 8) + (lane << 2));
                    }
                }
            }
#pragma unroll
            for (int r = 0; r < 4; ++r) {
                if (j0 < cnt_[r]) {
#pragma unroll
                    for (int q = 0; q < 4; ++q) {
                        int a01 = __builtin_amdgcn_readlane(pk01_[r], j0 + q);
                        int a23 = __builtin_amdgcn_readlane(pk23_[r], j0 + q);
                        h2 f01 = __builtin_bit_cast(h2, u[r][q].x);
                        h2 f23 = __builtin_bit_cast(h2, u[r][q].y);
                        h2 w01 = __builtin_bit_cast(h2, a01);
                        h2 w23 = __builtin_bit_cast(h2, a23);
                        if (q & 1) {
                            accC_[r] = __builtin_amdgcn_fdot2(f01, w01, accC_[r], false);
                            accD_[r] = __builtin_amdgcn_fdot2(f23, w23, accD_[r], false);
                        } else {
                            accA_[r] = __builtin_amdgcn_fdot2(f01, w01, accA_[r], false);
                            accB_[r] = __builtin_amdgcn_fdot2(f23, w23, accB_[r], false);
                        }
                    }
                }
            }
        }
#pragma unroll
        for (int r = 0; r < 4; ++r)
            out[(size_t)(nbase + r) * 64 + lane] =
                base_o[r] + ((accA_[r] + accC_[r]) + (accB_[r] + accD_[r]));
        return;
    }

    // slow path (any node with cnt in (64,128])
    for (int r = 0; r < 4; ++r) {
        int n = nbase + r;
        int cnt = cnt_[r];
        size_t start = (size_t)n << 7;
        if (cnt == 0) { out[(size_t)n * 64 + lane] = base_o[r]; continue; }
        float4 ern = *(const float4*)(er4 + 4 * (size_t)n);
        float4 den = {0.f, 0.f, 0.f, 0.f};
        for (int i0 = 0; i0 < cnt; i0 += 64) {
            int m = min(64, cnt - i0);
            float4 e4 = {0.f, 0.f, 0.f, 0.f};
            if (lane < m) {
                int sj = srcS[start + i0 + lane];
                float4 l = *(const float4*)(el4 + 4 * (size_t)sj);
                float x0 = l.x + ern.x, x1 = l.y + ern.y;
                float x2 = l.z + ern.z, x3 = l.w + ern.w;
                x0 = x0 > 0.f ? x0 : 0.2f * x0;
                x1 = x1 > 0.f ? x1 : 0.2f * x1;
                x2 = x2 > 0.f ? x2 : 0.2f * x2;
                x3 = x3 > 0.f ? x3 : 0.2f * x3;
                e4.x = __expf(x0); e4.y = __expf(x1);
                e4.z = __expf(x2); e4.w = __expf(x3);
            }
            den.x += e4.x; den.y += e4.y; den.z += e4.z; den.w += e4.w;
        }
#pragma unroll
        for (int off = 32; off; off >>= 1) {
            den.x += __shfl_xor(den.x, off);
            den.y += __shfl_xor(den.y, off);
            den.z += __shfl_xor(den.z, off);
            den.w += __shfl_xor(den.w, off);
        }
        float ivx = 0.25f * __builtin_amdgcn_rcpf(den.x);
        float ivy = 0.25f * __builtin_amdgcn_rcpf(den.y);
        float ivz = 0.25f * __builtin_amdgcn_rcpf(den.z);
        float ivw = 0.25f * __builtin_amdgcn_rcpf(den.w);
        float accA = 0.f, accB = 0.f;
        for (int i0 = 0; i0 < cnt; i0 += 64) {
            int m = min(64, cnt - i0);
            float4 e4 = {0.f, 0.f, 0.f, 0.f};
            int sj = 0;
            if (lane < m) {
                sj = srcS[start + i0 + lane];
                float4 l = *(const float4*)(el4 + 4 * (size_t)sj);
                float x0 = l.x + ern.x, x1 = l.y + ern.y;
                float x2 = l.z + ern.z, x3 = l.w + ern.w;
                x0 = x0 > 0.f ? x0 : 0.2f * x0;
                x1 = x1 > 0.f ? x1 : 0.2f * x1;
                x2 = x2 > 0.f ? x2 : 0.2f * x2;
                x3 = x3 > 0.f ? x3 : 0.2f * x3;
                e4.x = __expf(x0); e4.y = __expf(x1);
                e4.z = __expf(x2); e4.w = __expf(x3);
            }
            auto c01 = __builtin_amdgcn_cvt_pkrtz(e4.x * ivx, e4.y * ivy);
            auto c23 = __builtin_amdgcn_cvt_pkrtz(e4.z * ivz, e4.w * ivw);
            int pk01 = __builtin_bit_cast(int, c01);
            int pk23 = __builtin_bit_cast(int, c23);
            for (int j = 0; j < m; ++j) {
                int s = __builtin_amdgcn_readlane(sj, j);
                uint2 u = *(const uint2*)(featH + ((size_t)s << 8) + (lane << 2));
                int a01 = __builtin_amdgcn_readlane(pk01, j);
                int a23 = __builtin_amdgcn_readlane(pk23, j);
                accA = __builtin_amdgcn_fdot2(__builtin_bit_cast(h2, u.x),
                                              __builtin_bit_cast(h2, a01), accA, false);
                accB = __builtin_amdgcn_fdot2(__builtin_bit_cast(h2, u.y),
                                              __builtin_bit_cast(h2, a23), accB, false);
            }
        }
        out[(size_t)n * 64 + lane] = base_o[r] + accA + accB;
    }
}

extern "C" void kernel_launch(void* const* d_in, const int* in_sizes, int n_in,
                              void* d_out, int out_size, void* d_ws, size_t ws_size,
                              hipStream_t stream) {
    const float* emb   = (const float*)d_in[0];
    const float* Wfc   = (const float*)d_in[1];
    const float* attnl = (const float*)d_in[2];
    const float* attnr = (const float*)d_in[3];
    const float* Wres  = (const float*)d_in[4];
    const float* bias  = (const float*)d_in[5];
    const int*   src   = (const int*)d_in[6];
    const int*   dst   = (const int*)d_in[7];
    int N = in_sizes[0] / 64;
    int E = in_sizes[6];
    float* out = (float*)d_out;

    // workspace
    __half* featH  = (__half*)d_ws;                        // N*256 fp16
    float*  el4    = (float*)(featH + (size_t)N * 256);    // N*4
    float*  er4    = el4 + (size_t)N * 4;                  // N*4
    int*    counts = (int*)(er4 + (size_t)N * 4);          // N
    int*    srcS   = counts + N;                           // N*CAP

    (void)hipMemsetAsync(counts, 0, (size_t)N * sizeof(int), stream);

    hipLaunchKernelGGL(k1, dim3(NG + NH), dim3(256), 0, stream,
                       src, dst, counts, srcS, E,
                       emb, Wfc, attnl, attnr, featH, el4, er4, Wres, bias, out, N);
    hipLaunchKernelGGL(k_agg, dim3(N / 16), dim3(256), 0, stream,
                       counts, srcS, el4, er4, featH, out, N);
}